// Round 1
// 206.293 us; speedup vs baseline: 1.2241x; 1.2241x over previous
//
#include <hip/hip_runtime.h>
#include <stdint.h>

#define NPTS  8192
#define NB    4
#define KNN   20
#define NROWS (NB * NPTS)        // 32768
#define MTOTF 655360.0f          // NROWS * KNN
#define WPB   8                  // waves per block; all waves share the same 64 rows
#define BLK   (WPB * 64)         // 512 threads
#define SLICE (NPTS / WPB)       // 1024 candidates per wave
#define LSTR  (KNN + 1)          // padded merge-list stride
#define CAP   12                 // per-lane push-buffer slots (checked every 4 candidates)
#define NEG_INF -3.0e38f

__device__ __forceinline__ float med3f(float a, float b, float c) {
    return __builtin_amdgcn_fmed3f(a, b, c);
}

// Monotone float<->uint encoding so LDS atomicMax works as float-max (any sign).
__device__ __forceinline__ unsigned enc_f(float f) {
    unsigned u = __float_as_uint(f);
    return (u & 0x80000000u) ? ~u : (u | 0x80000000u);
}
__device__ __forceinline__ float dec_f(unsigned u) {
    return __uint_as_float((u & 0x80000000u) ? (u & 0x7fffffffu) : ~u);
}

// Insert t into descending top-KNN list (arr[0] = largest t = nearest point).
__device__ __forceinline__ void insert_t(float arr[KNN], float t) {
#pragma unroll
    for (int j = KNN - 1; j > 0; --j) arr[j] = med3f(t, arr[j - 1], arr[j]);
    arr[0] = fmaxf(arr[0], t);
}

// Drain this wave's push buffer into the register list; pad short lanes with
// NEG_INF (harmless insert). Publish new 20th-best to the shared threshold.
__device__ __forceinline__ void flush_buf(float arr[KNN], int& cnt,
    const float* bufw, int lane, unsigned* threshS) {
#pragma unroll
    for (int s = 0; s < CAP; ++s) {
        const float v = bufw[s * 64 + lane];
        insert_t(arr, (s < cnt) ? v : NEG_INF);
    }
    cnt = 0;
    atomicMax(&threshS[lane], enc_f(arr[KNN - 1]));
}

// Shared tail: wave 0 holds the merged descending-t list for row `row`.
// t = p.q - |q|^2/2, d2 = |p|^2 - 2t  (arr[0] = largest t = nearest).
__device__ __forceinline__ void finalize_row(
    float arr[KNN], float px, float py, float pz, int row, int lane,
    float* __restrict__ kmaxA, float* __restrict__ kminA, float* __restrict__ acc)
{
    const float pn2 = px * px + py * py + pz * pz;
    float sum = 0.f, sum2 = 0.f, dmin = 0.f, dmax = 0.f;
#pragma unroll
    for (int k = 0; k < KNN; ++k) {
        float d2 = fmaxf(fmaf(-2.f, arr[k], pn2), 0.f);
        float d = sqrtf(d2);
        sum += d; sum2 += d2;
        if (k == 0) dmin = d;
        dmax = d;
    }
    kmaxA[row] = dmax;
    kminA[row] = dmin;
#pragma unroll
    for (int o = 32; o; o >>= 1) {
        sum  += __shfl_down(sum,  o, 64);
        sum2 += __shfl_down(sum2, o, 64);
    }
    if (lane == 0) { atomicAdd(acc, sum); atomicAdd(acc + 1, sum2); }
}

// Prep: tile4[b*NPTS+m] = (qx, qy, qz, -|q|^2/2); zero the stats accumulator.
__global__ __launch_bounds__(256) void prep_kernel(
    const float* __restrict__ x, float4* __restrict__ tile4, float* __restrict__ acc)
{
    const int i = blockIdx.x * 256 + threadIdx.x;    // 0..32767
    const int b = i >> 13;
    const int m = i & (NPTS - 1);
    const float* xb = x + b * 3 * NPTS;
    const float qx = xb[m], qy = xb[NPTS + m], qz = xb[2 * NPTS + m];
    tile4[i] = make_float4(qx, qy, qz, -0.5f * (qx * qx + qy * qy + qz * qz));
    if (i < 2) acc[i] = 0.f;
}

// K1 (main): lane = row, candidates streamed through the SCALAR pipe.
// Buffered filtering: only candidates beating the shared per-row threshold
// (20th-best-so-far across ALL waves of this block, exact lower bound) pay
// the med3 insertion ladder; the rest cost ~6 VALU ops.
__global__ __launch_bounds__(BLK, 8) void knn_kernel(
    const float* __restrict__ x, const float4* __restrict__ tile4,
    float* __restrict__ kmaxA, float* __restrict__ kminA, float* __restrict__ acc)
{
    // Aliased LDS: push buffers (WPB*CAP*64 = 6144 floats) during the scan,
    // merge lists (7*64*21 = 9408 floats) after the drain barrier.
    __shared__ float shmem[(WPB - 1) * 64 * LSTR];   // 37632 B
    __shared__ unsigned threshS[64];                 // shared per-row threshold

    const int tid  = threadIdx.x;
    const int lane = tid & 63;
    const int wave = __builtin_amdgcn_readfirstlane(tid >> 6);
    const int rowBase = blockIdx.x * 64;
    const int row  = rowBase + lane;
    const int b    = rowBase >> 13;          // 128 blocks per batch
    const int n    = row & (NPTS - 1);
    const float* xb = x + b * 3 * NPTS;

    const float px = xb[n];
    const float py = xb[NPTS + n];
    const float pz = xb[2 * NPTS + n];

    if (tid < 64) threshS[tid] = enc_f(NEG_INF);

    float arr[KNN];
#pragma unroll
    for (int j = 0; j < KNN; ++j) arr[j] = NEG_INF;

    float* bufw = shmem + wave * (CAP * 64);   // [slot][lane] -> 2-way banks, free
    int cnt = 0;
    __syncthreads();

    const float4* __restrict__ tp = tile4 + b * NPTS + wave * SLICE;
    float th = NEG_INF;
    for (int c = 0; c < SLICE / 32; ++c) {
        // refresh shared threshold once per 32 candidates (stale = conservative)
        th = dec_f(*(volatile unsigned*)(threshS + lane));
        const float4* tq = tp + c * 32;
        for (int g = 0; g < 8; ++g) {
#pragma unroll
            for (int u = 0; u < 4; ++u) {
                const float4 q = tq[g * 4 + u];          // wave-uniform -> scalar load
                const float t = fmaf(q.x, px, fmaf(q.y, py, fmaf(q.z, pz, q.w)));
                if (t > th) { bufw[cnt * 64 + lane] = t; ++cnt; }
            }
            // entering a group with cnt<=CAP-4 guarantees writes stay in-bounds
            if (__any(cnt > CAP - 4)) {
                flush_buf(arr, cnt, bufw, lane, threshS);
                th = dec_f(*(volatile unsigned*)(threshS + lane));
            }
        }
    }
    if (__any(cnt > 0)) flush_buf(arr, cnt, bufw, lane, threshS);
    __syncthreads();   // all push-buffer use done before aliased list writes

    if (wave > 0) {
        float* dst = shmem + ((wave - 1) * 64 + lane) * LSTR;
#pragma unroll
        for (int j = 0; j < KNN; ++j) dst[j] = arr[j];
    }
    __syncthreads();

    if (wave == 0) {
        for (int wsrc = 0; wsrc < WPB - 1; ++wsrc) {
            const float* src = shmem + (wsrc * 64 + lane) * LSTR;
#pragma unroll
            for (int k = 0; k < KNN; ++k) insert_t(arr, src[k]);
        }
        finalize_row(arr, px, py, pz, row, lane, kmaxA, kminA, acc);
    }
}

// K1 (fallback, round-2 structure): used only if ws_size can't hold the tile.
__global__ __launch_bounds__(BLK) void knn_kernel_lds(
    const float* __restrict__ x,
    float* __restrict__ kmaxA, float* __restrict__ kminA, float* __restrict__ acc)
{
    __shared__ float4 tile[2048];
    __shared__ float  lists[(WPB - 1) * 64 * LSTR];

    const int tid  = threadIdx.x;
    const int lane = tid & 63;
    const int wave = tid >> 6;
    const int rowBase = blockIdx.x * 64;
    const int row  = rowBase + lane;
    const int b    = rowBase >> 13;
    const int n    = row & (NPTS - 1);
    const float* xb = x + b * 3 * NPTS;

    const float px = xb[n];
    const float py = xb[NPTS + n];
    const float pz = xb[2 * NPTS + n];

    float arr[KNN];
#pragma unroll
    for (int j = 0; j < KNN; ++j) arr[j] = NEG_INF;

    for (int t0 = 0; t0 < NPTS; t0 += 2048) {
        __syncthreads();
        const int i4 = tid * 4;
        const float4 qx4 = *(const float4*)(xb + t0 + i4);
        const float4 qy4 = *(const float4*)(xb + NPTS + t0 + i4);
        const float4 qz4 = *(const float4*)(xb + 2 * NPTS + t0 + i4);
        tile[i4 + 0] = make_float4(qx4.x, qy4.x, qz4.x, -0.5f * (qx4.x*qx4.x + qy4.x*qy4.x + qz4.x*qz4.x));
        tile[i4 + 1] = make_float4(qx4.y, qy4.y, qz4.y, -0.5f * (qx4.y*qx4.y + qy4.y*qy4.y + qz4.y*qz4.y));
        tile[i4 + 2] = make_float4(qx4.z, qy4.z, qz4.z, -0.5f * (qx4.z*qx4.z + qy4.z*qy4.z + qz4.z*qz4.z));
        tile[i4 + 3] = make_float4(qx4.w, qy4.w, qz4.w, -0.5f * (qx4.w*qx4.w + qy4.w*qy4.w + qz4.w*qz4.w));
        __syncthreads();
        const float4* base = tile + wave * 256;
#pragma unroll 4
        for (int i = 0; i < 256; ++i) {
            const float4 q = base[i];
            float t = fmaf(q.x, px, fmaf(q.y, py, fmaf(q.z, pz, q.w)));
            insert_t(arr, t);
        }
    }
    __syncthreads();

    if (wave > 0) {
        float* dst = lists + ((wave - 1) * 64 + lane) * LSTR;
#pragma unroll
        for (int j = 0; j < KNN; ++j) dst[j] = arr[j];
    }
    __syncthreads();

    if (wave == 0) {
        for (int wsrc = 0; wsrc < WPB - 1; ++wsrc) {
            const float* src = lists + (wsrc * 64 + lane) * LSTR;
#pragma unroll
            for (int k = 0; k < KNN; ++k) insert_t(arr, src[k]);
        }
        finalize_row(arr, px, py, pz, row, lane, kmaxA, kminA, acc);
    }
}

// K2: per-thread BN-coefficient computation (16 rsqrt, trivial) + output.
// out[b,c,n] = lrelu(a_c * (a_c>=0 ? kmax : kmin) + d_c)
__global__ __launch_bounds__(256) void out_kernel(
    const float* __restrict__ kmaxA, const float* __restrict__ kminA,
    const float* __restrict__ acc,
    const float* __restrict__ w, const float* __restrict__ gamma,
    const float* __restrict__ beta, float* __restrict__ out)
{
    const int r = blockIdx.x * 256 + threadIdx.x;   // 0..32767
    const int b = r >> 13;
    const int n = r & (NPTS - 1);
    const float mu  = acc[0] * (1.0f / MTOTF);
    float var = acc[1] * (1.0f / MTOTF) - mu * mu;
    var = fmaxf(var, 0.f);
    const float kmax = kmaxA[r];
    const float kmin = kminA[r];
#pragma unroll
    for (int c = 0; c < 16; ++c) {
        const float wc = w[c];
        const float a = gamma[c] * wc * rsqrtf(wc * wc * var + 1e-5f);
        const float d = beta[c] - a * mu;     // conv bias cancels inside BN
        float v = a * (a >= 0.f ? kmax : kmin) + d;
        v = (v >= 0.f) ? v : 0.2f * v;
        out[(b * 16 + c) * NPTS + n] = v;
    }
}

extern "C" void kernel_launch(void* const* d_in, const int* in_sizes, int n_in,
                              void* d_out, int out_size, void* d_ws, size_t ws_size,
                              hipStream_t stream)
{
    const float* x     = (const float*)d_in[0];
    const float* w     = (const float*)d_in[1];
    const float* gamma = (const float*)d_in[3];
    const float* beta  = (const float*)d_in[4];
    float* out = (float*)d_out;
    float* ws  = (float*)d_ws;

    float* kmaxA = ws;                       // NROWS floats
    float* kminA = ws + NROWS;               // NROWS floats
    float* acc   = ws + 2 * NROWS;           // 2 floats
    // tile at 16B-aligned float offset 2*NROWS+4
    float4* tile4 = (float4*)(ws + 2 * NROWS + 4);
    const size_t need = (size_t)(2 * NROWS + 4) * 4 + (size_t)NROWS * 16;

    if (ws_size >= need) {
        prep_kernel<<<NROWS / 256, 256, 0, stream>>>(x, tile4, acc);
        knn_kernel<<<NROWS / 64, BLK, 0, stream>>>(x, tile4, kmaxA, kminA, acc);
    } else {
        prep_kernel<<<1, 256, 0, stream>>>(x, tile4, acc);      // only zeroes acc
        knn_kernel_lds<<<NROWS / 64, BLK, 0, stream>>>(x, kmaxA, kminA, acc);
    }
    out_kernel<<<NROWS / 256, 256, 0, stream>>>(kmaxA, kminA, acc, w, gamma, beta, out);
}

// Round 2
// 202.535 us; speedup vs baseline: 1.2468x; 1.0186x over previous
//
#include <hip/hip_runtime.h>
#include <stdint.h>

#define NPTS  8192
#define NB    4
#define KNN   20
#define NROWS (NB * NPTS)        // 32768
#define MTOTF 655360.0f          // NROWS * KNN
#define WPB   8                  // waves per block; all waves share the same 64 rows
#define BLK   (WPB * 64)         // 512 threads
#define SLICE (NPTS / WPB)       // 1024 candidates per wave (fallback kernel)
#define HALF  (NPTS / 2)         // 4096 candidates per split block
#define SLICE2 (HALF / WPB)      // 512 candidates per wave (split kernel)
#define LSTR  (KNN + 1)          // padded merge-list stride
#define CAP   12                 // fallback push-buffer slots
#define CAP2  16                 // split-kernel push-buffer slots
#define NEG_INF -3.0e38f

__device__ __forceinline__ float med3f(float a, float b, float c) {
    return __builtin_amdgcn_fmed3f(a, b, c);
}

// Monotone float<->uint encoding so LDS atomicMax works as float-max (any sign).
__device__ __forceinline__ unsigned enc_f(float f) {
    unsigned u = __float_as_uint(f);
    return (u & 0x80000000u) ? ~u : (u | 0x80000000u);
}
__device__ __forceinline__ float dec_f(unsigned u) {
    return __uint_as_float((u & 0x80000000u) ? (u & 0x7fffffffu) : ~u);
}

// Insert t into descending top-KNN list (arr[0] = largest t = nearest point).
__device__ __forceinline__ void insert_t(float arr[KNN], float t) {
#pragma unroll
    for (int j = KNN - 1; j > 0; --j) arr[j] = med3f(t, arr[j - 1], arr[j]);
    arr[0] = fmaxf(arr[0], t);
}

// ---- fallback (round-1) flush: fixed CAP, padded ----
__device__ __forceinline__ void flush_buf(float arr[KNN], int& cnt,
    const float* bufw, int lane, unsigned* threshS) {
#pragma unroll
    for (int s = 0; s < CAP; ++s) {
        const float v = bufw[s * 64 + lane];
        insert_t(arr, (s < cnt) ? v : NEG_INF);
    }
    cnt = 0;
    atomicMax(&threshS[lane], enc_f(arr[KNN - 1]));
}

// ---- split-kernel flush: chunk-skippable (4 slots per uniform test) ----
__device__ __forceinline__ void flush_dyn(float arr[KNN], int& cnt,
    const float* bufw, int lane, unsigned* threshS) {
#pragma unroll
    for (int s0 = 0; s0 < CAP2; s0 += 4) {
        if (__any(cnt > s0)) {
#pragma unroll
            for (int s = s0; s < s0 + 4; ++s) {
                const float v = bufw[s * 64 + lane];
                insert_t(arr, (s < cnt) ? v : NEG_INF);
            }
        }
    }
    cnt = 0;
    atomicMax(&threshS[lane], enc_f(arr[KNN - 1]));
}

// Shared tail: caller holds the merged descending-t list for row `row`.
// t = p.q - |q|^2/2, d2 = |p|^2 - 2t  (arr[0] = largest t = nearest).
__device__ __forceinline__ void finalize_row(
    float arr[KNN], float px, float py, float pz, int row, int lane,
    float* __restrict__ kmaxA, float* __restrict__ kminA, float* __restrict__ acc)
{
    const float pn2 = px * px + py * py + pz * pz;
    float sum = 0.f, sum2 = 0.f, dmin = 0.f, dmax = 0.f;
#pragma unroll
    for (int k = 0; k < KNN; ++k) {
        float d2 = fmaxf(fmaf(-2.f, arr[k], pn2), 0.f);
        float d = sqrtf(d2);
        sum += d; sum2 += d2;
        if (k == 0) dmin = d;
        dmax = d;
    }
    kmaxA[row] = dmax;
    kminA[row] = dmin;
#pragma unroll
    for (int o = 32; o; o >>= 1) {
        sum  += __shfl_down(sum,  o, 64);
        sum2 += __shfl_down(sum2, o, 64);
    }
    if (lane == 0) { atomicAdd(acc, sum); atomicAdd(acc + 1, sum2); }
}

// Prep: tile4[b*NPTS+m] = (qx, qy, qz, -|q|^2/2); zero the stats accumulator.
__global__ __launch_bounds__(256) void prep_kernel(
    const float* __restrict__ x, float4* __restrict__ tile4, float* __restrict__ acc)
{
    const int i = blockIdx.x * 256 + threadIdx.x;    // 0..32767
    const int b = i >> 13;
    const int m = i & (NPTS - 1);
    const float* xb = x + b * 3 * NPTS;
    const float qx = xb[m], qy = xb[NPTS + m], qz = xb[2 * NPTS + m];
    tile4[i] = make_float4(qx, qy, qz, -0.5f * (qx * qx + qy * qy + qz * qz));
    if (i < 2) acc[i] = 0.f;
}

// K1 (main, split): grid = 1024 blocks = (512 row-groups) x (2 candidate halves)
// -> 4 blocks/CU = 32 waves/CU (100% occupancy cap). Each block produces a
// sorted partial top-20 per row over its 4096-candidate half.
// Inner loop is branchless: always-store push + conditional count increment.
__global__ __launch_bounds__(BLK, 8) void knn_split_kernel(
    const float* __restrict__ x, const float4* __restrict__ tile4,
    float* __restrict__ part)
{
    // Aliased LDS: push buffers (WPB*CAP2*64 = 8192 floats) during the scan,
    // merge lists (7*64*21 = 9408 floats) after the drain barrier.
    __shared__ float shmem[(WPB - 1) * 64 * LSTR];   // 37632 B
    __shared__ unsigned threshS[64];                 // shared per-row threshold

    const int tid  = threadIdx.x;
    const int lane = tid & 63;
    const int wave = __builtin_amdgcn_readfirstlane(tid >> 6);
    const int rb   = blockIdx.x >> 1;        // row-group 0..511
    const int half = blockIdx.x & 1;         // candidate half
    const int rowBase = rb * 64;
    const int row  = rowBase + lane;
    const int b    = rowBase >> 13;          // 128 row-groups per batch
    const int n    = row & (NPTS - 1);
    const float* xb = x + b * 3 * NPTS;

    const float px = xb[n];
    const float py = xb[NPTS + n];
    const float pz = xb[2 * NPTS + n];

    if (tid < 64) threshS[tid] = enc_f(NEG_INF);

    float arr[KNN];
#pragma unroll
    for (int j = 0; j < KNN; ++j) arr[j] = NEG_INF;

    float* bufw = shmem + wave * (CAP2 * 64);   // [slot][lane] -> 2-way banks, free
    __syncthreads();

    const float4* __restrict__ tp = tile4 + b * NPTS + half * HALF + wave * SLICE2;

    // Warm-up: direct-insert first 32 candidates, publish a REAL 20-of-32
    // threshold (kills the -inf cold-start flood of the buffered path).
#pragma unroll 8
    for (int i = 0; i < 32; ++i) {
        const float4 q = tp[i];
        insert_t(arr, fmaf(q.x, px, fmaf(q.y, py, fmaf(q.z, pz, q.w))));
    }
    atomicMax(&threshS[lane], enc_f(arr[KNN - 1]));

    int cnt = 0;
    for (int c = 1; c < SLICE2 / 32; ++c) {
        // refresh shared threshold once per 32 candidates (stale = conservative)
        float th = dec_f(*(volatile unsigned*)(threshS + lane));
        const float4* tq = tp + c * 32;
        for (int g = 0; g < 8; ++g) {
#pragma unroll
            for (int u = 0; u < 4; ++u) {
                const float4 q = tq[g * 4 + u];          // wave-uniform -> scalar load
                const float t = fmaf(q.x, px, fmaf(q.y, py, fmaf(q.z, pz, q.w)));
                bufw[cnt * 64 + lane] = t;               // always-store (no branch)
                cnt += (t > th);
            }
            // entering a group with cnt<=CAP2-4 guarantees writes stay in-bounds
            if (__any(cnt > CAP2 - 4)) {
                flush_dyn(arr, cnt, bufw, lane, threshS);
                th = dec_f(*(volatile unsigned*)(threshS + lane));
            }
        }
    }
    if (__any(cnt > 0)) flush_dyn(arr, cnt, bufw, lane, threshS);
    __syncthreads();   // all push-buffer use done before aliased list writes

    if (wave > 0) {
        float* dst = shmem + ((wave - 1) * 64 + lane) * LSTR;
#pragma unroll
        for (int j = 0; j < KNN; ++j) dst[j] = arr[j];
    }
    __syncthreads();

    if (wave == 0) {
        for (int wsrc = 0; wsrc < WPB - 1; ++wsrc) {
            const float* src = shmem + (wsrc * 64 + lane) * LSTR;
#pragma unroll
            for (int k = 0; k < KNN; ++k) insert_t(arr, src[k]);
        }
        // write sorted partial list: part[(row*2+half)*20 .. +19], 80B-aligned
        float4* dst = (float4*)(part + (row * 2 + half) * KNN);
#pragma unroll
        for (int k = 0; k < KNN; k += 4)
            dst[k >> 2] = make_float4(arr[k], arr[k + 1], arr[k + 2], arr[k + 3]);
    }
}

// K1b: merge the two sorted partial lists per row, then finalize
// (kmax/kmin + BN-stat atomics). One thread per row.
__global__ __launch_bounds__(256) void merge_kernel(
    const float* __restrict__ x, const float* __restrict__ part,
    float* __restrict__ kmaxA, float* __restrict__ kminA, float* __restrict__ acc)
{
    const int r = blockIdx.x * 256 + threadIdx.x;   // 0..32767
    const int lane = threadIdx.x & 63;
    const int b = r >> 13;
    const int n = r & (NPTS - 1);
    const float* xb = x + b * 3 * NPTS;
    const float px = xb[n];
    const float py = xb[NPTS + n];
    const float pz = xb[2 * NPTS + n];

    const float4* pA = (const float4*)(part + r * 2 * KNN);
    float arr[KNN];
#pragma unroll
    for (int k = 0; k < KNN; k += 4) {
        const float4 v = pA[k >> 2];
        arr[k] = v.x; arr[k + 1] = v.y; arr[k + 2] = v.z; arr[k + 3] = v.w;
    }
#pragma unroll
    for (int k = 0; k < KNN; k += 4) {
        const float4 v = pA[(KNN + k) >> 2];
        insert_t(arr, v.x); insert_t(arr, v.y); insert_t(arr, v.z); insert_t(arr, v.w);
    }
    finalize_row(arr, px, py, pz, r, lane, kmaxA, kminA, acc);
}

// ---- fallback K1 (round-1, verified): single block per 64 rows ----
__global__ __launch_bounds__(BLK, 8) void knn_kernel(
    const float* __restrict__ x, const float4* __restrict__ tile4,
    float* __restrict__ kmaxA, float* __restrict__ kminA, float* __restrict__ acc)
{
    __shared__ float shmem[(WPB - 1) * 64 * LSTR];
    __shared__ unsigned threshS[64];

    const int tid  = threadIdx.x;
    const int lane = tid & 63;
    const int wave = __builtin_amdgcn_readfirstlane(tid >> 6);
    const int rowBase = blockIdx.x * 64;
    const int row  = rowBase + lane;
    const int b    = rowBase >> 13;
    const int n    = row & (NPTS - 1);
    const float* xb = x + b * 3 * NPTS;

    const float px = xb[n];
    const float py = xb[NPTS + n];
    const float pz = xb[2 * NPTS + n];

    if (tid < 64) threshS[tid] = enc_f(NEG_INF);

    float arr[KNN];
#pragma unroll
    for (int j = 0; j < KNN; ++j) arr[j] = NEG_INF;

    float* bufw = shmem + wave * (CAP * 64);
    int cnt = 0;
    __syncthreads();

    const float4* __restrict__ tp = tile4 + b * NPTS + wave * SLICE;
    float th = NEG_INF;
    for (int c = 0; c < SLICE / 32; ++c) {
        th = dec_f(*(volatile unsigned*)(threshS + lane));
        const float4* tq = tp + c * 32;
        for (int g = 0; g < 8; ++g) {
#pragma unroll
            for (int u = 0; u < 4; ++u) {
                const float4 q = tq[g * 4 + u];
                const float t = fmaf(q.x, px, fmaf(q.y, py, fmaf(q.z, pz, q.w)));
                if (t > th) { bufw[cnt * 64 + lane] = t; ++cnt; }
            }
            if (__any(cnt > CAP - 4)) {
                flush_buf(arr, cnt, bufw, lane, threshS);
                th = dec_f(*(volatile unsigned*)(threshS + lane));
            }
        }
    }
    if (__any(cnt > 0)) flush_buf(arr, cnt, bufw, lane, threshS);
    __syncthreads();

    if (wave > 0) {
        float* dst = shmem + ((wave - 1) * 64 + lane) * LSTR;
#pragma unroll
        for (int j = 0; j < KNN; ++j) dst[j] = arr[j];
    }
    __syncthreads();

    if (wave == 0) {
        for (int wsrc = 0; wsrc < WPB - 1; ++wsrc) {
            const float* src = shmem + (wsrc * 64 + lane) * LSTR;
#pragma unroll
            for (int k = 0; k < KNN; ++k) insert_t(arr, src[k]);
        }
        finalize_row(arr, px, py, pz, row, lane, kmaxA, kminA, acc);
    }
}

// K1 (fallback, LDS tile): used only if ws_size can't hold the tile.
__global__ __launch_bounds__(BLK) void knn_kernel_lds(
    const float* __restrict__ x,
    float* __restrict__ kmaxA, float* __restrict__ kminA, float* __restrict__ acc)
{
    __shared__ float4 tile[2048];
    __shared__ float  lists[(WPB - 1) * 64 * LSTR];

    const int tid  = threadIdx.x;
    const int lane = tid & 63;
    const int wave = tid >> 6;
    const int rowBase = blockIdx.x * 64;
    const int row  = rowBase + lane;
    const int b    = rowBase >> 13;
    const int n    = row & (NPTS - 1);
    const float* xb = x + b * 3 * NPTS;

    const float px = xb[n];
    const float py = xb[NPTS + n];
    const float pz = xb[2 * NPTS + n];

    float arr[KNN];
#pragma unroll
    for (int j = 0; j < KNN; ++j) arr[j] = NEG_INF;

    for (int t0 = 0; t0 < NPTS; t0 += 2048) {
        __syncthreads();
        const int i4 = tid * 4;
        const float4 qx4 = *(const float4*)(xb + t0 + i4);
        const float4 qy4 = *(const float4*)(xb + NPTS + t0 + i4);
        const float4 qz4 = *(const float4*)(xb + 2 * NPTS + t0 + i4);
        tile[i4 + 0] = make_float4(qx4.x, qy4.x, qz4.x, -0.5f * (qx4.x*qx4.x + qy4.x*qy4.x + qz4.x*qz4.x));
        tile[i4 + 1] = make_float4(qx4.y, qy4.y, qz4.y, -0.5f * (qx4.y*qx4.y + qy4.y*qy4.y + qz4.y*qz4.y));
        tile[i4 + 2] = make_float4(qx4.z, qy4.z, qz4.z, -0.5f * (qx4.z*qx4.z + qy4.z*qy4.z + qz4.z*qz4.z));
        tile[i4 + 3] = make_float4(qx4.w, qy4.w, qz4.w, -0.5f * (qx4.w*qx4.w + qy4.w*qy4.w + qz4.w*qz4.w));
        __syncthreads();
        const float4* base = tile + wave * 256;
#pragma unroll 4
        for (int i = 0; i < 256; ++i) {
            const float4 q = base[i];
            float t = fmaf(q.x, px, fmaf(q.y, py, fmaf(q.z, pz, q.w)));
            insert_t(arr, t);
        }
    }
    __syncthreads();

    if (wave > 0) {
        float* dst = lists + ((wave - 1) * 64 + lane) * LSTR;
#pragma unroll
        for (int j = 0; j < KNN; ++j) dst[j] = arr[j];
    }
    __syncthreads();

    if (wave == 0) {
        for (int wsrc = 0; wsrc < WPB - 1; ++wsrc) {
            const float* src = lists + (wsrc * 64 + lane) * LSTR;
#pragma unroll
            for (int k = 0; k < KNN; ++k) insert_t(arr, src[k]);
        }
        finalize_row(arr, px, py, pz, row, lane, kmaxA, kminA, acc);
    }
}

// K2: per-thread BN-coefficient computation (16 rsqrt, trivial) + output.
// out[b,c,n] = lrelu(a_c * (a_c>=0 ? kmax : kmin) + d_c)
__global__ __launch_bounds__(256) void out_kernel(
    const float* __restrict__ kmaxA, const float* __restrict__ kminA,
    const float* __restrict__ acc,
    const float* __restrict__ w, const float* __restrict__ gamma,
    const float* __restrict__ beta, float* __restrict__ out)
{
    const int r = blockIdx.x * 256 + threadIdx.x;   // 0..32767
    const int b = r >> 13;
    const int n = r & (NPTS - 1);
    const float mu  = acc[0] * (1.0f / MTOTF);
    float var = acc[1] * (1.0f / MTOTF) - mu * mu;
    var = fmaxf(var, 0.f);
    const float kmax = kmaxA[r];
    const float kmin = kminA[r];
#pragma unroll
    for (int c = 0; c < 16; ++c) {
        const float wc = w[c];
        const float a = gamma[c] * wc * rsqrtf(wc * wc * var + 1e-5f);
        const float d = beta[c] - a * mu;     // conv bias cancels inside BN
        float v = a * (a >= 0.f ? kmax : kmin) + d;
        v = (v >= 0.f) ? v : 0.2f * v;
        out[(b * 16 + c) * NPTS + n] = v;
    }
}

extern "C" void kernel_launch(void* const* d_in, const int* in_sizes, int n_in,
                              void* d_out, int out_size, void* d_ws, size_t ws_size,
                              hipStream_t stream)
{
    const float* x     = (const float*)d_in[0];
    const float* w     = (const float*)d_in[1];
    const float* gamma = (const float*)d_in[3];
    const float* beta  = (const float*)d_in[4];
    float* out = (float*)d_out;
    float* ws  = (float*)d_ws;

    float* kmaxA = ws;                       // NROWS floats
    float* kminA = ws + NROWS;               // NROWS floats
    float* acc   = ws + 2 * NROWS;           // 2 floats
    // tile at 16B-aligned float offset 2*NROWS+4
    float4* tile4 = (float4*)(ws + 2 * NROWS + 4);
    float* part = ws + (2 * NROWS + 4) + 4 * NROWS;   // 32768*40 floats, 16B-aligned
    const size_t need_tile  = (size_t)(2 * NROWS + 4) * 4 + (size_t)NROWS * 16;
    const size_t need_split = need_tile + (size_t)NROWS * 2 * KNN * 4;

    if (ws_size >= need_split) {
        prep_kernel<<<NROWS / 256, 256, 0, stream>>>(x, tile4, acc);
        knn_split_kernel<<<2 * (NROWS / 64), BLK, 0, stream>>>(x, tile4, part);
        merge_kernel<<<NROWS / 256, 256, 0, stream>>>(x, part, kmaxA, kminA, acc);
    } else if (ws_size >= need_tile) {
        prep_kernel<<<NROWS / 256, 256, 0, stream>>>(x, tile4, acc);
        knn_kernel<<<NROWS / 64, BLK, 0, stream>>>(x, tile4, kmaxA, kminA, acc);
    } else {
        prep_kernel<<<1, 256, 0, stream>>>(x, tile4, acc);      // only zeroes acc
        knn_kernel_lds<<<NROWS / 64, BLK, 0, stream>>>(x, kmaxA, kminA, acc);
    }
    out_kernel<<<NROWS / 256, 256, 0, stream>>>(kmaxA, kminA, acc, w, gamma, beta, out);
}